// Round 1
// baseline (3112.032 us; speedup 1.0000x reference)
//
#include <hip/hip_runtime.h>

#define BB 64
#define SS 4096
#define DD 64
#define FF 256
#define INVS 0.35355339059327373f   // 1/sqrt(8) = 64^-0.25
#define FSCALE 0.0625f              // 256^-0.5

// workspace layout (float-index offsets)
#define KV_OFF_F    0                          // [BB][FF][DD]
#define KSUM_OFF_F  (BB*FF*DD)                 // [BB][FF]
#define MKEY_OFF_F  (KSUM_OFF_F + BB*FF)       // [BB] uint keys (true max k_proj)
#define NKEY_OFF_F  (MKEY_OFF_F + BB)          // [BB] uint keys (max raw row |k|^2)
#define MSUM_OFF_F  (NKEY_OFF_F + BB)          // [BB][DD] column sums of raw k
#define WS_ZERO_F   (MSUM_OFF_F + BB*DD)
#define WS_ZERO_BYTES (WS_ZERO_F * 4)

__device__ __forceinline__ unsigned fkey(float f) {
    unsigned b = __float_as_uint(f);
    return (f < 0.0f) ? ~b : (b | 0x80000000u);
}
__device__ __forceinline__ float funkey(unsigned k) {
    return (k & 0x80000000u) ? __uint_as_float(k ^ 0x80000000u) : __uint_as_float(~k);
}

// ---------------------------------------------------------------------------
// K1: per-b column sums of raw k (for mean) + max raw row-norm^2
// grid (4, 64), block 256
// ---------------------------------------------------------------------------
__global__ __launch_bounds__(256) void k_stats(const float* __restrict__ kin,
                                               float* __restrict__ msum,
                                               unsigned* __restrict__ nkey) {
    const int b = blockIdx.y, chunk = blockIdx.x;
    const int t = threadIdx.x, i = t & 63, r = t >> 6;
    const float* kb = kin + (size_t)b * (SS * DD);
    float sacc = 0.0f, nmax = 0.0f;
    const int s0 = chunk * 1024;
    for (int s = s0 + r; s < s0 + 1024; s += 4) {
        float v = kb[s * DD + i];
        sacc += v;
        float sq = v * v;                       // row-norm^2: wave = one row
        #pragma unroll
        for (int off = 32; off; off >>= 1) sq += __shfl_xor(sq, off);
        nmax = fmaxf(nmax, sq);
    }
    __shared__ float red[4][64];
    red[r][i] = sacc;
    __syncthreads();
    if (r == 0) {
        float m = red[0][i] + red[1][i] + red[2][i] + red[3][i];
        atomicAdd(&msum[b * DD + i], m);
    }
    if (i == 0) atomicMax(&nkey[b], fkey(nmax));   // nmax wave-uniform
}

// ---------------------------------------------------------------------------
// K3: phi_k with safe normalizer Mhat; accumulate ksum_hat, kv_hat; record true
//     max k_proj. grid (8, 64), block 256.
// ---------------------------------------------------------------------------
__global__ __launch_bounds__(256, 2) void k_kv(const float* __restrict__ kin,
                                               const float* __restrict__ vin,
                                               const float* __restrict__ w,
                                               float* __restrict__ ws) {
    float* kv = ws + KV_OFF_F;
    float* ksum = ws + KSUM_OFF_F;
    unsigned* mkey = (unsigned*)ws + MKEY_OFF_F;
    const unsigned* nkey = (const unsigned*)ws + NKEY_OFF_F;
    const float* msum = ws + MSUM_OFF_F;

    const int b = blockIdx.y, chunk = blockIdx.x;
    const int t = threadIdx.x, i = t & 63, r = t >> 6;   // also (d=i, c=r) in accum role

    __shared__ __align__(16) float kbuf[DD * 4];    // [i][r]
    __shared__ __align__(16) float vbuf[4 * DD];    // [r][d]
    __shared__ __align__(16) float phibuf[FF * 4];  // [f][r]
    __shared__ float meanl[DD];
    __shared__ float cbuf[4];
    __shared__ float redw[4];
    __shared__ float mhat_s;

    if (t < 64) {
        float mv = msum[t + b * DD] * (1.0f / 4096.0f);
        meanl[t] = mv;
        float sq = mv * mv;
        #pragma unroll
        for (int off = 32; off; off >>= 1) sq += __shfl_xor(sq, off);
        if (t == 0) {
            float nrm = sqrtf(funkey(nkey[b]));
            mhat_s = (nrm + sqrtf(sq)) * INVS;      // >= true max k_proj
        }
    }
    float wreg[64];                                 // w row for f = t, in registers
    {
        const float4* w4 = (const float4*)w + t * 16;
        #pragma unroll
        for (int j = 0; j < 16; ++j) {
            float4 x = w4[j];
            wreg[4*j] = x.x; wreg[4*j+1] = x.y; wreg[4*j+2] = x.z; wreg[4*j+3] = x.w;
        }
    }
    __syncthreads();
    const float mhat = mhat_s;
    const float* kb = kin + (size_t)b * (SS * DD);
    const float* vb = vin + (size_t)b * (SS * DD);

    float kvacc[64];
    #pragma unroll
    for (int j = 0; j < 64; ++j) kvacc[j] = 0.0f;
    float ksacc = 0.0f, dmax = -1e30f;

    for (int s0 = chunk * 512; s0 < chunk * 512 + 512; s0 += 4) {
        float kval = (kb[(s0 + r) * DD + i] - meanl[i]) * INVS;
        vbuf[r * DD + i] = vb[(s0 + r) * DD + i];
        kbuf[i * 4 + r] = kval;
        float sq = kval * kval;
        #pragma unroll
        for (int off = 32; off; off >>= 1) sq += __shfl_xor(sq, off);
        if (i == 0) cbuf[r] = 0.5f * sq;
        __syncthreads();

        float d0 = 0, d1 = 0, d2 = 0, d3 = 0;       // proj role: f = t
        #pragma unroll
        for (int ii = 0; ii < 64; ++ii) {
            float wv = wreg[ii];
            float4 k4 = *(const float4*)&kbuf[ii * 4];
            d0 = fmaf(wv, k4.x, d0); d1 = fmaf(wv, k4.y, d1);
            d2 = fmaf(wv, k4.z, d2); d3 = fmaf(wv, k4.w, d3);
        }
        dmax = fmaxf(dmax, fmaxf(fmaxf(d0, d1), fmaxf(d2, d3)));
        float p0 = __expf(d0 - cbuf[0] - mhat) * FSCALE;
        float p1 = __expf(d1 - cbuf[1] - mhat) * FSCALE;
        float p2 = __expf(d2 - cbuf[2] - mhat) * FSCALE;
        float p3 = __expf(d3 - cbuf[3] - mhat) * FSCALE;
        ksacc += (p0 + p1) + (p2 + p3);
        *(float4*)&phibuf[t * 4] = make_float4(p0, p1, p2, p3);
        __syncthreads();

        // accum role: thread owns (d=i, f-chunk c=r): kv[c*64+j][d]
        float v0 = vbuf[0 * DD + i], v1 = vbuf[1 * DD + i];
        float v2 = vbuf[2 * DD + i], v3 = vbuf[3 * DD + i];
        #pragma unroll
        for (int j = 0; j < 64; ++j) {
            float4 p = *(const float4*)&phibuf[(r * 64 + j) * 4];
            kvacc[j] = fmaf(p.x, v0, fmaf(p.y, v1, fmaf(p.z, v2, fmaf(p.w, v3, kvacc[j]))));
        }
        __syncthreads();
    }
    #pragma unroll
    for (int j = 0; j < 64; ++j)
        atomicAdd(&kv[((size_t)b * FF + (r * 64 + j)) * DD + i], kvacc[j]);   // lanes: d coalesced
    atomicAdd(&ksum[b * FF + t], ksacc);
    #pragma unroll
    for (int off = 32; off; off >>= 1) dmax = fmaxf(dmax, __shfl_xor(dmax, off));
    if ((t & 63) == 0) redw[t >> 6] = dmax;
    __syncthreads();
    if (t == 0) {
        float m = fmaxf(fmaxf(redw[0], redw[1]), fmaxf(redw[2], redw[3]));
        atomicMax(&mkey[b], fkey(m));
    }
}

// ---------------------------------------------------------------------------
// K4: phi_q, deno (with alpha rescale inside the clamp), out = phi_q . kv / deno
// grid (8, 64), block 256.
// ---------------------------------------------------------------------------
__global__ __launch_bounds__(256, 2) void k_out(const float* __restrict__ qin,
                                                const float* __restrict__ w,
                                                const float* __restrict__ ws,
                                                float* __restrict__ outp) {
    const float* kv = ws + KV_OFF_F;
    const float* ksum = ws + KSUM_OFF_F;
    const unsigned* mkey = (const unsigned*)ws + MKEY_OFF_F;
    const unsigned* nkey = (const unsigned*)ws + NKEY_OFF_F;
    const float* msum = ws + MSUM_OFF_F;

    const int b = blockIdx.y, chunk = blockIdx.x;
    const int t = threadIdx.x, i = t & 63, r = t >> 6;

    __shared__ __align__(16) float qbuf[DD * 4];     // [i][r]
    __shared__ __align__(16) float phibuf[FF * 4];   // [f][r]
    __shared__ __align__(16) float part[4 * DD * 4]; // [c][d][r]
    __shared__ __align__(16) float redm[16];         // [wave][r] row maxes
    __shared__ __align__(16) float redd[16];         // [wave][r] deno partials
    __shared__ float cbuf[4];
    __shared__ float alpha_s;

    if (t < 64) {
        float mv = msum[t + b * DD] * (1.0f / 4096.0f);
        float sq = mv * mv;
        #pragma unroll
        for (int off = 32; off; off >>= 1) sq += __shfl_xor(sq, off);
        if (t == 0) {
            float nrm = sqrtf(funkey(nkey[b]));
            float mhat = (nrm + sqrtf(sq)) * INVS;   // identical formula to K3
            float mtrue = funkey(mkey[b]);
            alpha_s = __expf(mhat - mtrue);          // alpha >= 1
        }
    }
    float wreg[64];
    {
        const float4* w4 = (const float4*)w + t * 16;
        #pragma unroll
        for (int j = 0; j < 16; ++j) {
            float4 x = w4[j];
            wreg[4*j] = x.x; wreg[4*j+1] = x.y; wreg[4*j+2] = x.z; wreg[4*j+3] = x.w;
        }
    }
    float kvreg[64];                                 // kv[c*64+j][d] column cache
    #pragma unroll
    for (int j = 0; j < 64; ++j)
        kvreg[j] = kv[((size_t)b * FF + (r * 64 + j)) * DD + i];
    const float ksumf = ksum[b * FF + t];
    __syncthreads();
    const float alpha = alpha_s;
    const float* qb = qin + (size_t)b * (SS * DD);
    float* ob = outp + (size_t)b * (SS * DD);

    for (int s0 = chunk * 512; s0 < chunk * 512 + 512; s0 += 4) {
        float qv = qb[(s0 + r) * DD + i] * INVS;
        qbuf[i * 4 + r] = qv;
        float sq = qv * qv;
        #pragma unroll
        for (int off = 32; off; off >>= 1) sq += __shfl_xor(sq, off);
        if (i == 0) cbuf[r] = 0.5f * sq;
        __syncthreads();

        float d0 = 0, d1 = 0, d2 = 0, d3 = 0;        // proj role: f = t
        #pragma unroll
        for (int ii = 0; ii < 64; ++ii) {
            float wv = wreg[ii];
            float4 q4 = *(const float4*)&qbuf[ii * 4];
            d0 = fmaf(wv, q4.x, d0); d1 = fmaf(wv, q4.y, d1);
            d2 = fmaf(wv, q4.z, d2); d3 = fmaf(wv, q4.w, d3);
        }
        // block max over f per row
        float m0 = d0, m1 = d1, m2 = d2, m3 = d3;
        #pragma unroll
        for (int off = 32; off; off >>= 1) {
            m0 = fmaxf(m0, __shfl_xor(m0, off)); m1 = fmaxf(m1, __shfl_xor(m1, off));
            m2 = fmaxf(m2, __shfl_xor(m2, off)); m3 = fmaxf(m3, __shfl_xor(m3, off));
        }
        if ((t & 63) == 0) *(float4*)&redm[(t >> 6) * 4] = make_float4(m0, m1, m2, m3);
        __syncthreads();
        float mx0 = -1e30f, mx1 = -1e30f, mx2 = -1e30f, mx3 = -1e30f;
        #pragma unroll
        for (int wv = 0; wv < 4; ++wv) {
            float4 m4 = *(const float4*)&redm[wv * 4];
            mx0 = fmaxf(mx0, m4.x); mx1 = fmaxf(mx1, m4.y);
            mx2 = fmaxf(mx2, m4.z); mx3 = fmaxf(mx3, m4.w);
        }
        float p0 = __expf(d0 - cbuf[0] - mx0) * FSCALE;
        float p1 = __expf(d1 - cbuf[1] - mx1) * FSCALE;
        float p2 = __expf(d2 - cbuf[2] - mx2) * FSCALE;
        float p3 = __expf(d3 - cbuf[3] - mx3) * FSCALE;
        // deno partials
        float t0 = p0 * ksumf, t1 = p1 * ksumf, t2 = p2 * ksumf, t3 = p3 * ksumf;
        #pragma unroll
        for (int off = 32; off; off >>= 1) {
            t0 += __shfl_xor(t0, off); t1 += __shfl_xor(t1, off);
            t2 += __shfl_xor(t2, off); t3 += __shfl_xor(t3, off);
        }
        if ((t & 63) == 0) *(float4*)&redd[(t >> 6) * 4] = make_float4(t0, t1, t2, t3);
        *(float4*)&phibuf[t * 4] = make_float4(p0, p1, p2, p3);
        __syncthreads();
        float s0d = 0, s1d = 0, s2d = 0, s3d = 0;
        #pragma unroll
        for (int wv = 0; wv < 4; ++wv) {
            float4 t4 = *(const float4*)&redd[wv * 4];
            s0d += t4.x; s1d += t4.y; s2d += t4.z; s3d += t4.w;
        }
        const float dn0 = fmaxf(s0d * alpha, 1e-4f), dn1 = fmaxf(s1d * alpha, 1e-4f);
        const float dn2 = fmaxf(s2d * alpha, 1e-4f), dn3 = fmaxf(s3d * alpha, 1e-4f);

        // out role: thread (d=i, f-chunk c=r)
        float a0 = 0, a1 = 0, a2 = 0, a3 = 0;
        #pragma unroll
        for (int j = 0; j < 64; ++j) {
            float4 p = *(const float4*)&phibuf[(r * 64 + j) * 4];
            float kvv = kvreg[j];
            a0 = fmaf(p.x, kvv, a0); a1 = fmaf(p.y, kvv, a1);
            a2 = fmaf(p.z, kvv, a2); a3 = fmaf(p.w, kvv, a3);
        }
        *(float4*)&part[(r * 64 + i) * 4] = make_float4(a0, a1, a2, a3);
        __syncthreads();
        {
            const int r2 = t >> 6, d2 = t & 63;
            float o = part[(0 * 64 + d2) * 4 + r2] + part[(1 * 64 + d2) * 4 + r2] +
                      part[(2 * 64 + d2) * 4 + r2] + part[(3 * 64 + d2) * 4 + r2];
            const float dn = (r2 == 0) ? dn0 : (r2 == 1) ? dn1 : (r2 == 2) ? dn2 : dn3;
            ob[(size_t)(s0 + r2) * DD + d2] = o * alpha / dn;
        }
        __syncthreads();
    }
}

extern "C" void kernel_launch(void* const* d_in, const int* in_sizes, int n_in,
                              void* d_out, int out_size, void* d_ws, size_t ws_size,
                              hipStream_t stream) {
    (void)in_sizes; (void)n_in; (void)out_size; (void)ws_size;
    const float* q = (const float*)d_in[0];
    const float* k = (const float*)d_in[1];
    const float* v = (const float*)d_in[2];
    const float* w = (const float*)d_in[3];
    float* out = (float*)d_out;
    float* ws = (float*)d_ws;

    hipMemsetAsync(d_ws, 0, WS_ZERO_BYTES, stream);
    k_stats<<<dim3(4, 64), 256, 0, stream>>>(k, ws + MSUM_OFF_F, (unsigned*)ws + NKEY_OFF_F);
    k_kv<<<dim3(8, 64), 256, 0, stream>>>(k, v, w, ws);
    k_out<<<dim3(8, 64), 256, 0, stream>>>(q, w, ws, out);
}

// Round 2
// 1225.610 us; speedup vs baseline: 2.5392x; 2.5392x over previous
//
#include <hip/hip_runtime.h>

#define BB 64
#define SS 4096
#define DD 64
#define FF 256
#define INVS 0.35355339059327373f   // 1/sqrt(8) = 64^-0.25
#define FSCALE 0.0625f              // 256^-0.5

// workspace layout (float-index offsets)
#define KV_OFF_F    0                          // [BB][FF][DD]
#define KSUM_OFF_F  (BB*FF*DD)                 // [BB][FF]
#define MKEY_OFF_F  (KSUM_OFF_F + BB*FF)       // [BB] uint keys (true max k_proj)
#define NKEY_OFF_F  (MKEY_OFF_F + BB)          // [BB] uint keys (max raw row |k|^2)
#define MSUM_OFF_F  (NKEY_OFF_F + BB)          // [BB][DD] column sums of raw k
#define WS_ZERO_F   (MSUM_OFF_F + BB*DD)
#define WS_ZERO_BYTES (WS_ZERO_F * 4)

__device__ __forceinline__ unsigned fkey(float f) {
    unsigned b = __float_as_uint(f);
    return (f < 0.0f) ? ~b : (b | 0x80000000u);
}
__device__ __forceinline__ float funkey(unsigned k) {
    return (k & 0x80000000u) ? __uint_as_float(k ^ 0x80000000u) : __uint_as_float(~k);
}

// ---------------------------------------------------------------------------
// K1: per-b column sums of raw k (for mean) + max raw row-norm^2
// grid (4, 64), block 256  (unchanged from round 1; negligible time)
// ---------------------------------------------------------------------------
__global__ __launch_bounds__(256) void k_stats(const float* __restrict__ kin,
                                               float* __restrict__ msum,
                                               unsigned* __restrict__ nkey) {
    const int b = blockIdx.y, chunk = blockIdx.x;
    const int t = threadIdx.x, i = t & 63, r = t >> 6;
    const float* kb = kin + (size_t)b * (SS * DD);
    float sacc = 0.0f, nmax = 0.0f;
    const int s0 = chunk * 1024;
    for (int s = s0 + r; s < s0 + 1024; s += 4) {
        float v = kb[s * DD + i];
        sacc += v;
        float sq = v * v;
        #pragma unroll
        for (int off = 32; off; off >>= 1) sq += __shfl_xor(sq, off);
        nmax = fmaxf(nmax, sq);
    }
    __shared__ float red[4][64];
    red[r][i] = sacc;
    __syncthreads();
    if (r == 0) {
        float m = red[0][i] + red[1][i] + red[2][i] + red[3][i];
        atomicAdd(&msum[b * DD + i], m);
    }
    if (i == 0) atomicMax(&nkey[b], fkey(nmax));
}

// ---------------------------------------------------------------------------
// K2: phi_k^T V.  Thread owns f = tid: w row + kv accumulator in registers.
// Rows staged 32 at a time in LDS (broadcast reads). grid (8, 64), block 256.
// ---------------------------------------------------------------------------
__global__ __launch_bounds__(256, 2) void k_kv(const float* __restrict__ kin,
                                               const float* __restrict__ vin,
                                               const float* __restrict__ w,
                                               float* __restrict__ ws) {
    float* kv = ws + KV_OFF_F;
    float* ksum = ws + KSUM_OFF_F;
    unsigned* mkey = (unsigned*)ws + MKEY_OFF_F;
    const unsigned* nkey = (const unsigned*)ws + NKEY_OFF_F;
    const float* msum = ws + MSUM_OFF_F;

    const int b = blockIdx.y, chunk = blockIdx.x;
    const int t = threadIdx.x;

    __shared__ __align__(16) float kst[32 * 64];
    __shared__ __align__(16) float vst[32 * 64];
    __shared__ float cst[32];
    __shared__ float muL[64];
    __shared__ float mhatL;
    __shared__ __align__(16) float kvT[64 * 65];   // padded transpose buffer
    __shared__ float redw[4];

    if (t < 64) {
        float mv = msum[b * DD + t] * (1.0f / 4096.0f);
        muL[t] = mv;
        float sq = mv * mv;
        #pragma unroll
        for (int off = 32; off; off >>= 1) sq += __shfl_xor(sq, off);
        if (t == 0) mhatL = (sqrtf(funkey(nkey[b])) + sqrtf(sq)) * INVS;
    }
    float wreg[64];                                 // w row for f = t
    {
        const float4* w4 = (const float4*)w + t * 16;
        #pragma unroll
        for (int j = 0; j < 16; ++j) {
            float4 x = w4[j];
            wreg[4*j] = x.x; wreg[4*j+1] = x.y; wreg[4*j+2] = x.z; wreg[4*j+3] = x.w;
        }
    }
    __syncthreads();
    const float mhat = mhatL;
    const float4 mu4 = *(const float4*)&muL[(t & 15) * 4];

    float kvacc[64];
    #pragma unroll
    for (int j = 0; j < 64; ++j) kvacc[j] = 0.0f;
    float ksacc = 0.0f, dmax = -1e30f;

    const float4* kg = (const float4*)kin + ((size_t)b * SS + chunk * 512) * 16;
    const float4* vg = (const float4*)vin + ((size_t)b * SS + chunk * 512) * 16;

    // prefetch stage 0
    float4 ka = kg[t], kb4 = kg[t + 256];
    float4 va = vg[t], vb4 = vg[t + 256];

    for (int st = 0; st < 16; ++st) {
        __syncthreads();   // everyone done consuming previous stage
        // process current regs -> LDS
        ka.x = (ka.x - mu4.x) * INVS; ka.y = (ka.y - mu4.y) * INVS;
        ka.z = (ka.z - mu4.z) * INVS; ka.w = (ka.w - mu4.w) * INVS;
        kb4.x = (kb4.x - mu4.x) * INVS; kb4.y = (kb4.y - mu4.y) * INVS;
        kb4.z = (kb4.z - mu4.z) * INVS; kb4.w = (kb4.w - mu4.w) * INVS;
        float sqa = ka.x*ka.x + ka.y*ka.y + ka.z*ka.z + ka.w*ka.w;
        float sqb = kb4.x*kb4.x + kb4.y*kb4.y + kb4.z*kb4.z + kb4.w*kb4.w;
        *(float4*)&kst[t * 4] = ka;
        *(float4*)&kst[(t + 256) * 4] = kb4;
        *(float4*)&vst[t * 4] = va;
        *(float4*)&vst[(t + 256) * 4] = vb4;
        #pragma unroll
        for (int off = 1; off <= 8; off <<= 1) {
            sqa += __shfl_xor(sqa, off);
            sqb += __shfl_xor(sqb, off);
        }
        if ((t & 15) == 0) { cst[t >> 4] = 0.5f * sqa; cst[16 + (t >> 4)] = 0.5f * sqb; }
        __syncthreads();   // stage visible
        // prefetch next stage (overlaps compute)
        if (st < 15) {
            const int base = (st + 1) * 512;
            ka = kg[base + t]; kb4 = kg[base + t + 256];
            va = vg[base + t]; vb4 = vg[base + t + 256];
        }
        #pragma unroll 2
        for (int r = 0; r < 32; ++r) {
            const float c = cst[r];
            float d0 = 0, d1 = 0, d2 = 0, d3 = 0;
            #pragma unroll
            for (int ii = 0; ii < 16; ++ii) {
                float4 k4 = *(const float4*)&kst[r * 64 + ii * 4];
                d0 = fmaf(wreg[4*ii],   k4.x, d0);
                d1 = fmaf(wreg[4*ii+1], k4.y, d1);
                d2 = fmaf(wreg[4*ii+2], k4.z, d2);
                d3 = fmaf(wreg[4*ii+3], k4.w, d3);
            }
            const float d = (d0 + d1) + (d2 + d3);
            dmax = fmaxf(dmax, d);
            const float p = __expf(d - c - mhat) * FSCALE;
            ksacc += p;
            #pragma unroll
            for (int jj = 0; jj < 16; ++jj) {
                float4 v4 = *(const float4*)&vst[r * 64 + jj * 4];
                kvacc[4*jj]   = fmaf(p, v4.x, kvacc[4*jj]);
                kvacc[4*jj+1] = fmaf(p, v4.y, kvacc[4*jj+1]);
                kvacc[4*jj+2] = fmaf(p, v4.z, kvacc[4*jj+2]);
                kvacc[4*jj+3] = fmaf(p, v4.w, kvacc[4*jj+3]);
            }
        }
    }
    // epilogue: ksum + true-max + coalesced kv atomics via padded LDS transpose
    atomicAdd(&ksum[b * FF + t], ksacc);
    #pragma unroll
    for (int off = 32; off; off >>= 1) dmax = fmaxf(dmax, __shfl_xor(dmax, off));
    if ((t & 63) == 0) redw[t >> 6] = dmax;
    __syncthreads();
    if (t == 0) {
        float m = fmaxf(fmaxf(redw[0], redw[1]), fmaxf(redw[2], redw[3]));
        atomicMax(&mkey[b], fkey(m));
    }
    float* kvb0 = &kv[(size_t)b * FF * DD];
    for (int pass = 0; pass < 4; ++pass) {
        __syncthreads();
        if ((t >> 6) == pass) {
            const int fl = t & 63;
            #pragma unroll
            for (int u = 0; u < 16; ++u)
                *(float4*)&kvT[fl * 65 + 4 * u] =
                    make_float4(kvacc[4*u], kvacc[4*u+1], kvacc[4*u+2], kvacc[4*u+3]);
        }
        __syncthreads();
        float* kvb = kvb0 + pass * 64 * DD;
        #pragma unroll
        for (int u = 0; u < 16; ++u) {
            const int flat = u * 256 + t;
            atomicAdd(&kvb[flat], kvT[(flat >> 6) * 65 + (flat & 63)]);
        }
    }
}

// ---------------------------------------------------------------------------
// K3: out = phi_q . kv / deno.  Thread owns one full row; w + kv + ksum in LDS
// (pure broadcast reads), q row + o accumulator in registers. No barriers or
// shuffles in the f-loop: per-row normalizer bound mhat=||x||, true max folded
// back via alpha inside the clamp. grid (8, 64), block 512, 129 KB LDS.
// ---------------------------------------------------------------------------
__global__ __launch_bounds__(512, 2) void k_out(const float* __restrict__ qin,
                                                const float* __restrict__ w,
                                                const float* __restrict__ ws,
                                                float* __restrict__ outp) {
    const float* kv = ws + KV_OFF_F;
    const float* ksum = ws + KSUM_OFF_F;
    const unsigned* mkey = (const unsigned*)ws + MKEY_OFF_F;
    const unsigned* nkey = (const unsigned*)ws + NKEY_OFF_F;
    const float* msum = ws + MSUM_OFF_F;

    const int b = blockIdx.y, chunk = blockIdx.x, t = threadIdx.x;

    __shared__ __align__(16) float wL[FF * DD];     // 64 KB
    __shared__ __align__(16) float kvL[FF * DD];    // 64 KB
    __shared__ __align__(16) float ksL[FF];         // 1 KB
    __shared__ float abL;

    if (t < 64) {
        float mv = msum[b * DD + t] * (1.0f / 4096.0f);
        float sq = mv * mv;
        #pragma unroll
        for (int off = 32; off; off >>= 1) sq += __shfl_xor(sq, off);
        if (t == 0) {
            float mhat = (sqrtf(funkey(nkey[b])) + sqrtf(sq)) * INVS;  // same ops as k_kv
            abL = __expf(mhat - funkey(mkey[b]));                      // alpha_b >= 1
        }
    }
    {
        const float4* w4 = (const float4*)w;
        const float4* kv4 = (const float4*)(kv + (size_t)b * FF * DD);
        #pragma unroll
        for (int u = 0; u < 8; ++u) {
            ((float4*)wL)[u * 512 + t] = w4[u * 512 + t];
            ((float4*)kvL)[u * 512 + t] = kv4[u * 512 + t];
        }
        if (t < 64) ((float4*)ksL)[t] = ((const float4*)(ksum + b * FF))[t];
    }
    // q row into registers (scaled); csum = ||x||^2
    float q[64];
    const int row = chunk * 512 + t;
    const float4* qg = (const float4*)qin + ((size_t)b * SS + row) * 16;
    float csum = 0.0f;
    #pragma unroll
    for (int u = 0; u < 16; ++u) {
        float4 x = qg[u];
        x.x *= INVS; x.y *= INVS; x.z *= INVS; x.w *= INVS;
        q[4*u] = x.x; q[4*u+1] = x.y; q[4*u+2] = x.z; q[4*u+3] = x.w;
        csum += x.x*x.x + x.y*x.y + x.z*x.z + x.w*x.w;
    }
    const float c = 0.5f * csum;
    const float mhatq = sqrtf(csum);                // ||x|| >= max_f <x, w_f>
    __syncthreads();
    const float alpha_b = abL;

    float o[64];
    #pragma unroll
    for (int j = 0; j < 64; ++j) o[j] = 0.0f;
    float deno = 0.0f, mtrue = -1e30f;

    #pragma unroll 2
    for (int f = 0; f < FF; ++f) {
        float d0 = 0, d1 = 0, d2 = 0, d3 = 0;
        #pragma unroll
        for (int ii = 0; ii < 16; ++ii) {
            float4 wv = *(const float4*)&wL[f * 64 + 4 * ii];
            d0 = fmaf(wv.x, q[4*ii],   d0);
            d1 = fmaf(wv.y, q[4*ii+1], d1);
            d2 = fmaf(wv.z, q[4*ii+2], d2);
            d3 = fmaf(wv.w, q[4*ii+3], d3);
        }
        const float d = (d0 + d1) + (d2 + d3);
        mtrue = fmaxf(mtrue, d);
        const float p = __expf(d - c - mhatq);
        deno = fmaf(p, ksL[f], deno);
        #pragma unroll
        for (int jj = 0; jj < 16; ++jj) {
            float4 kvv = *(const float4*)&kvL[f * 64 + 4 * jj];
            o[4*jj]   = fmaf(p, kvv.x, o[4*jj]);
            o[4*jj+1] = fmaf(p, kvv.y, o[4*jj+1]);
            o[4*jj+2] = fmaf(p, kvv.z, o[4*jj+2]);
            o[4*jj+3] = fmaf(p, kvv.w, o[4*jj+3]);
        }
    }
    const float A = alpha_b * __expf(mhatq - mtrue) * FSCALE;
    const float dn = fmaxf(A * deno, 1e-4f);
    const float scale = A / dn;
    float4* og = (float4*)outp + ((size_t)b * SS + row) * 16;
    #pragma unroll
    for (int u = 0; u < 16; ++u)
        og[u] = make_float4(o[4*u] * scale, o[4*u+1] * scale,
                            o[4*u+2] * scale, o[4*u+3] * scale);
}

extern "C" void kernel_launch(void* const* d_in, const int* in_sizes, int n_in,
                              void* d_out, int out_size, void* d_ws, size_t ws_size,
                              hipStream_t stream) {
    (void)in_sizes; (void)n_in; (void)out_size; (void)ws_size;
    const float* q = (const float*)d_in[0];
    const float* k = (const float*)d_in[1];
    const float* v = (const float*)d_in[2];
    const float* w = (const float*)d_in[3];
    float* out = (float*)d_out;
    float* ws = (float*)d_ws;

    hipMemsetAsync(d_ws, 0, WS_ZERO_BYTES, stream);
    k_stats<<<dim3(4, 64), 256, 0, stream>>>(k, ws + MSUM_OFF_F, (unsigned*)ws + NKEY_OFF_F);
    k_kv<<<dim3(8, 64), 256, 0, stream>>>(k, v, w, ws);
    k_out<<<dim3(8, 64), 512, 0, stream>>>(q, w, ws, out);
}

// Round 3
// 705.974 us; speedup vs baseline: 4.4081x; 1.7361x over previous
//
#include <hip/hip_runtime.h>

#define BB 64
#define SS 4096
#define DD 64
#define FF 256
#define INVS 0.35355339059327373f   // 1/sqrt(8) = 64^-0.25
#define FSCALE 0.0625f              // 256^-0.5

// workspace layout (float-index offsets)
#define KV_OFF_F    0                          // [BB][FF][DD]
#define KSUM_OFF_F  (BB*FF*DD)                 // [BB][FF]
#define MKEY_OFF_F  (KSUM_OFF_F + BB*FF)       // [BB] uint keys (true max k_proj)
#define NKEY_OFF_F  (MKEY_OFF_F + BB)          // [BB] uint keys (max raw row |k|^2)
#define MSUM_OFF_F  (NKEY_OFF_F + BB)          // [BB][DD] column sums of raw k
#define WS_ZERO_F   (MSUM_OFF_F + BB*DD)
#define WS_ZERO_BYTES (WS_ZERO_F * 4)

typedef _Float16 f16;
typedef __attribute__((ext_vector_type(4))) _Float16 f16x4;
typedef __attribute__((ext_vector_type(8))) _Float16 f16x8;
typedef __attribute__((ext_vector_type(4))) float f32x4;

__device__ __forceinline__ unsigned fkey(float f) {
    unsigned b = __float_as_uint(f);
    return (f < 0.0f) ? ~b : (b | 0x80000000u);
}
__device__ __forceinline__ float funkey(unsigned k) {
    return (k & 0x80000000u) ? __uint_as_float(k ^ 0x80000000u) : __uint_as_float(~k);
}
__device__ __forceinline__ void splitf(float x, f16& h, f16& l) {
    h = (f16)x;
    l = (f16)(x - (float)h);
}

// ---------------------------------------------------------------------------
// K1: per-b column sums of raw k (mean) + max raw row-norm^2.
// grid (16, 64), block 256. Vectorized: wave covers 4 rows per iter.
// ---------------------------------------------------------------------------
__global__ __launch_bounds__(256) void k_stats(const float* __restrict__ kin,
                                               float* __restrict__ msum,
                                               unsigned* __restrict__ nkey) {
    const int b = blockIdx.y, chunk = blockIdx.x;
    const int t = threadIdx.x, row = t >> 4, c16 = t & 15;
    const float4* kg = (const float4*)(kin + (size_t)b * (SS * DD));
    float4 cacc = make_float4(0.f, 0.f, 0.f, 0.f);
    float nmax = 0.f;
    const int s0 = chunk * 256;
    #pragma unroll 4
    for (int it = 0; it < 16; ++it) {
        const int s = s0 + it * 16 + row;
        float4 x = kg[s * 16 + c16];
        cacc.x += x.x; cacc.y += x.y; cacc.z += x.z; cacc.w += x.w;
        float sq = x.x * x.x + x.y * x.y + x.z * x.z + x.w * x.w;
        #pragma unroll
        for (int off = 1; off <= 8; off <<= 1) sq += __shfl_xor(sq, off);
        nmax = fmaxf(nmax, sq);
    }
    __shared__ float csum[64];
    __shared__ float wm[4];
    if (t < 64) csum[t] = 0.f;
    __syncthreads();
    atomicAdd(&csum[c16 * 4 + 0], cacc.x);
    atomicAdd(&csum[c16 * 4 + 1], cacc.y);
    atomicAdd(&csum[c16 * 4 + 2], cacc.z);
    atomicAdd(&csum[c16 * 4 + 3], cacc.w);
    nmax = fmaxf(nmax, __shfl_xor(nmax, 16));
    nmax = fmaxf(nmax, __shfl_xor(nmax, 32));
    if ((t & 63) == 0) wm[t >> 6] = nmax;
    __syncthreads();
    if (t < 64) atomicAdd(&msum[b * DD + t], csum[t]);
    if (t == 0) {
        float mx = fmaxf(fmaxf(wm[0], wm[1]), fmaxf(wm[2], wm[3]));
        atomicMax(&nkey[b], fkey(mx));
    }
}

// ---------------------------------------------------------------------------
// K2 (MFMA): phi_k^T V via two chained 16x16x32 f16 MFMA GEMMs with hi/lo
// split (3 products, lo*lo dropped). Phase A: P[32s x 256f] = K_c * W^T.
// exp in C-layout regs; P -> LDS in A-operand layout (pT[f][s]).
// Phase B: kv[256f x 64d] += P^T * V, acc persistent in VGPRs.
// grid (4, 64), block 512 (8 waves), ~62 KB LDS, 1 block/CU.
// ---------------------------------------------------------------------------
__global__ __launch_bounds__(512, 1) void k_kv(const float* __restrict__ kin,
                                               const float* __restrict__ vin,
                                               const float* __restrict__ w,
                                               float* __restrict__ ws) {
    float* kv = ws + KV_OFF_F;
    float* ksum = ws + KSUM_OFF_F;
    unsigned* mkey = (unsigned*)ws + MKEY_OFF_F;
    const unsigned* nkey = (const unsigned*)ws + NKEY_OFF_F;
    const float* msum = ws + MSUM_OFF_F;

    const int b = blockIdx.y, chunk = blockIdx.x;
    const int t = threadIdx.x;
    const int wid = t >> 6, l = t & 63, quad = l >> 4, m = l & 15;
    const int st = wid & 1, fgroup = wid >> 1;   // phase-A tile mapping

    // rows padded: kH 72 (bank-stride 36==4 mod 32 -> 2-way free), pT/vT 40 (20 mod 32 -> 2-way)
    __shared__ __align__(16) f16 kH[32 * 72], kL[32 * 72];
    __shared__ __align__(16) f16 vTH[64 * 40], vTL[64 * 40];
    __shared__ __align__(16) f16 pTH[256 * 40], pTL[256 * 40];
    __shared__ __align__(16) float cS[32];
    __shared__ __align__(16) float muL[64];
    __shared__ float ksumL[256];
    __shared__ float redw[8];
    __shared__ float mhatL;

    if (t < 64) {
        float mv = msum[b * DD + t] * (1.0f / 4096.0f);
        muL[t] = mv;
        float sq = mv * mv;
        #pragma unroll
        for (int off = 32; off; off >>= 1) sq += __shfl_xor(sq, off);
        if (t == 0) mhatL = (sqrtf(funkey(nkey[b])) + sqrtf(sq)) * INVS;
    }
    if (t < 256) ksumL[t] = 0.f;

    // W fragments (phase-A B-operand) held in registers for the whole kernel:
    // lane needs w[f = ft*16 + m][d = ks*32 + quad*8 + j], j=0..7.
    f16x8 wbH[4][2], wbL[4][2];
    #pragma unroll
    for (int ff = 0; ff < 4; ++ff) {
        #pragma unroll
        for (int ks = 0; ks < 2; ++ks) {
            const float* wp = w + (((fgroup * 4 + ff) * 16 + m) * 64 + ks * 32 + quad * 8);
            float4 x0 = *(const float4*)wp;
            float4 x1 = *(const float4*)(wp + 4);
            f16 h, lo;
            splitf(x0.x, h, lo); wbH[ff][ks][0] = h; wbL[ff][ks][0] = lo;
            splitf(x0.y, h, lo); wbH[ff][ks][1] = h; wbL[ff][ks][1] = lo;
            splitf(x0.z, h, lo); wbH[ff][ks][2] = h; wbL[ff][ks][2] = lo;
            splitf(x0.w, h, lo); wbH[ff][ks][3] = h; wbL[ff][ks][3] = lo;
            splitf(x1.x, h, lo); wbH[ff][ks][4] = h; wbL[ff][ks][4] = lo;
            splitf(x1.y, h, lo); wbH[ff][ks][5] = h; wbL[ff][ks][5] = lo;
            splitf(x1.z, h, lo); wbH[ff][ks][6] = h; wbL[ff][ks][6] = lo;
            splitf(x1.w, h, lo); wbH[ff][ks][7] = h; wbL[ff][ks][7] = lo;
        }
    }
    __syncthreads();
    const float mhat = mhatL;
    const int srow = t >> 4, scol = t & 15;          // staging: row 0..31, float4 col
    const float4 mu4 = *(const float4*)&muL[scol * 4];

    f32x4 acc2[8];                                   // phase-B acc: 2 f-tiles x 4 d-tiles
    #pragma unroll
    for (int i = 0; i < 8; ++i) acc2[i] = (f32x4){0.f, 0.f, 0.f, 0.f};
    float dmax = -1e30f;

    const int rbase = chunk * 1024;
    const float4* kg = (const float4*)(kin + (size_t)b * (SS * DD));
    const float4* vg = (const float4*)(vin + (size_t)b * (SS * DD));

    float4 k4 = kg[(rbase + srow) * 16 + scol];
    float4 v4 = vg[(rbase + srow) * 16 + scol];

    for (int it = 0; it < 32; ++it) {
        // ---- stage current regs -> LDS (center+scale k in fp32, split to f16) ----
        float4 kc;
        kc.x = (k4.x - mu4.x) * INVS; kc.y = (k4.y - mu4.y) * INVS;
        kc.z = (k4.z - mu4.z) * INVS; kc.w = (k4.w - mu4.w) * INVS;
        float sq = kc.x * kc.x + kc.y * kc.y + kc.z * kc.z + kc.w * kc.w;
        #pragma unroll
        for (int off = 1; off <= 8; off <<= 1) sq += __shfl_xor(sq, off);
        if (scol == 0) cS[srow] = 0.5f * sq;
        {
            f16x4 khv, klv;
            f16 h, lo;
            splitf(kc.x, h, lo); khv[0] = h; klv[0] = lo;
            splitf(kc.y, h, lo); khv[1] = h; klv[1] = lo;
            splitf(kc.z, h, lo); khv[2] = h; klv[2] = lo;
            splitf(kc.w, h, lo); khv[3] = h; klv[3] = lo;
            *(f16x4*)&kH[srow * 72 + scol * 4] = khv;
            *(f16x4*)&kL[srow * 72 + scol * 4] = klv;
        }
        #pragma unroll
        for (int u = 0; u < 4; ++u) {
            float vv = (&v4.x)[u];
            f16 vh, vl;
            splitf(vv, vh, vl);
            vTH[(scol * 4 + u) * 40 + srow] = vh;    // transposed for B-operand
            vTL[(scol * 4 + u) * 40 + srow] = vl;
        }
        __syncthreads();

        // ---- phase A: P tile = K_c * W^T, then exp -> pT (A-layout) ----
        f16x8 aH[2], aL[2];
        #pragma unroll
        for (int ks = 0; ks < 2; ++ks) {
            aH[ks] = *(const f16x8*)&kH[(st * 16 + m) * 72 + ks * 32 + quad * 8];
            aL[ks] = *(const f16x8*)&kL[(st * 16 + m) * 72 + ks * 32 + quad * 8];
        }
        const float4 c4 = *(const float4*)&cS[st * 16 + quad * 4];
        const int s0 = st * 16 + quad * 4;
        #pragma unroll
        for (int ff = 0; ff < 4; ++ff) {
            f32x4 acc = (f32x4){0.f, 0.f, 0.f, 0.f};
            #pragma unroll
            for (int ks = 0; ks < 2; ++ks) {
                acc = __builtin_amdgcn_mfma_f32_16x16x32_f16(aH[ks], wbH[ff][ks], acc, 0, 0, 0);
                acc = __builtin_amdgcn_mfma_f32_16x16x32_f16(aH[ks], wbL[ff][ks], acc, 0, 0, 0);
                acc = __builtin_amdgcn_mfma_f32_16x16x32_f16(aL[ks], wbH[ff][ks], acc, 0, 0, 0);
            }
            float ksp = 0.f;
            f16x4 phv, plv;
            #pragma unroll
            for (int r = 0; r < 4; ++r) {
                float d = acc[r];
                dmax = fmaxf(dmax, d);
                float p = __expf(d - (&c4.x)[r] - mhat) * FSCALE;
                ksp += p;
                f16 h, lo;
                splitf(p, h, lo);
                phv[r] = h; plv[r] = lo;
            }
            const int f = (fgroup * 4 + ff) * 16 + m;
            *(f16x4*)&pTH[f * 40 + s0] = phv;        // 4 consecutive s (= regs)
            *(f16x4*)&pTL[f * 40 + s0] = plv;
            ksp += __shfl_xor(ksp, 16);
            ksp += __shfl_xor(ksp, 32);
            if (l < 16) atomicAdd(&ksumL[(fgroup * 4 + ff) * 16 + l], ksp);
        }
        __syncthreads();

        // prefetch next stage (overlaps phase B)
        if (it < 31) {
            k4 = kg[(rbase + (it + 1) * 32 + srow) * 16 + scol];
            v4 = vg[(rbase + (it + 1) * 32 + srow) * 16 + scol];
        }

        // ---- phase B: kv += P^T * V (K = 32 = this stage's rows) ----
        f16x8 aH2[2], aL2[2], bH2[4], bL2[4];
        #pragma unroll
        for (int tt = 0; tt < 2; ++tt) {
            const int f = (wid * 2 + tt) * 16 + m;
            aH2[tt] = *(const f16x8*)&pTH[f * 40 + quad * 8];
            aL2[tt] = *(const f16x8*)&pTL[f * 40 + quad * 8];
        }
        #pragma unroll
        for (int dt = 0; dt < 4; ++dt) {
            const int d = dt * 16 + m;
            bH2[dt] = *(const f16x8*)&vTH[d * 40 + quad * 8];
            bL2[dt] = *(const f16x8*)&vTL[d * 40 + quad * 8];
        }
        #pragma unroll
        for (int tt = 0; tt < 2; ++tt) {
            #pragma unroll
            for (int dt = 0; dt < 4; ++dt) {
                f32x4 a = acc2[tt * 4 + dt];
                a = __builtin_amdgcn_mfma_f32_16x16x32_f16(aH2[tt], bH2[dt], a, 0, 0, 0);
                a = __builtin_amdgcn_mfma_f32_16x16x32_f16(aH2[tt], bL2[dt], a, 0, 0, 0);
                a = __builtin_amdgcn_mfma_f32_16x16x32_f16(aL2[tt], bH2[dt], a, 0, 0, 0);
                acc2[tt * 4 + dt] = a;
            }
        }
        __syncthreads();
    }

    // ---- epilogue: kv atomics (C-layout: row=f, col=d), ksum, true max ----
    #pragma unroll
    for (int tt = 0; tt < 2; ++tt) {
        #pragma unroll
        for (int dt = 0; dt < 4; ++dt) {
            #pragma unroll
            for (int r = 0; r < 4; ++r) {
                const int f = (wid * 2 + tt) * 16 + quad * 4 + r;
                const int d = dt * 16 + m;
                atomicAdd(&kv[((size_t)b * FF + f) * DD + d], acc2[tt * 4 + dt][r]);
            }
        }
    }
    if (t < 256) atomicAdd(&ksum[b * FF + t], ksumL[t]);
    #pragma unroll
    for (int off = 32; off; off >>= 1) dmax = fmaxf(dmax, __shfl_xor(dmax, off));
    if (l == 0) redw[wid] = dmax;
    __syncthreads();
    if (t == 0) {
        float mx = redw[0];
        #pragma unroll
        for (int i = 1; i < 8; ++i) mx = fmaxf(mx, redw[i]);
        atomicMax(&mkey[b], fkey(mx));
    }
}

// ---------------------------------------------------------------------------
// K3: out = phi_q . kv / deno (unchanged from round 2 — proven).
// grid (8, 64), block 512, 129 KB LDS.
// ---------------------------------------------------------------------------
__global__ __launch_bounds__(512, 2) void k_out(const float* __restrict__ qin,
                                                const float* __restrict__ w,
                                                const float* __restrict__ ws,
                                                float* __restrict__ outp) {
    const float* kv = ws + KV_OFF_F;
    const float* ksum = ws + KSUM_OFF_F;
    const unsigned* mkey = (const unsigned*)ws + MKEY_OFF_F;
    const unsigned* nkey = (const unsigned*)ws + NKEY_OFF_F;
    const float* msum = ws + MSUM_OFF_F;

    const int b = blockIdx.y, chunk = blockIdx.x, t = threadIdx.x;

    __shared__ __align__(16) float wL[FF * DD];     // 64 KB
    __shared__ __align__(16) float kvL[FF * DD];    // 64 KB
    __shared__ __align__(16) float ksL[FF];         // 1 KB
    __shared__ float abL;

    if (t < 64) {
        float mv = msum[b * DD + t] * (1.0f / 4096.0f);
        float sq = mv * mv;
        #pragma unroll
        for (int off = 32; off; off >>= 1) sq += __shfl_xor(sq, off);
        if (t == 0) {
            float mhat = (sqrtf(funkey(nkey[b])) + sqrtf(sq)) * INVS;  // same ops as k_kv
            abL = __expf(mhat - funkey(mkey[b]));                      // alpha_b >= 1
        }
    }
    {
        const float4* w4 = (const float4*)w;
        const float4* kv4 = (const float4*)(kv + (size_t)b * FF * DD);
        #pragma unroll
        for (int u = 0; u < 8; ++u) {
            ((float4*)wL)[u * 512 + t] = w4[u * 512 + t];
            ((float4*)kvL)[u * 512 + t] = kv4[u * 512 + t];
        }
        if (t < 64) ((float4*)ksL)[t] = ((const float4*)(ksum + b * FF))[t];
    }
    float q[64];
    const int row = chunk * 512 + t;
    const float4* qg = (const float4*)qin + ((size_t)b * SS + row) * 16;
    float csum = 0.0f;
    #pragma unroll
    for (int u = 0; u < 16; ++u) {
        float4 x = qg[u];
        x.x *= INVS; x.y *= INVS; x.z *= INVS; x.w *= INVS;
        q[4*u] = x.x; q[4*u+1] = x.y; q[4*u+2] = x.z; q[4*u+3] = x.w;
        csum += x.x*x.x + x.y*x.y + x.z*x.z + x.w*x.w;
    }
    const float c = 0.5f * csum;
    const float mhatq = sqrtf(csum);                // ||x|| >= max_f <x, w_f>
    __syncthreads();
    const float alpha_b = abL;

    float o[64];
    #pragma unroll
    for (int j = 0; j < 64; ++j) o[j] = 0.0f;
    float deno = 0.0f, mtrue = -1e30f;

    #pragma unroll 2
    for (int f = 0; f < FF; ++f) {
        float d0 = 0, d1 = 0, d2 = 0, d3 = 0;
        #pragma unroll
        for (int ii = 0; ii < 16; ++ii) {
            float4 wv = *(const float4*)&wL[f * 64 + 4 * ii];
            d0 = fmaf(wv.x, q[4*ii],   d0);
            d1 = fmaf(wv.y, q[4*ii+1], d1);
            d2 = fmaf(wv.z, q[4*ii+2], d2);
            d3 = fmaf(wv.w, q[4*ii+3], d3);
        }
        const float d = (d0 + d1) + (d2 + d3);
        mtrue = fmaxf(mtrue, d);
        const float p = __expf(d - c - mhatq);
        deno = fmaf(p, ksL[f], deno);
        #pragma unroll
        for (int jj = 0; jj < 16; ++jj) {
            float4 kvv = *(const float4*)&kvL[f * 64 + 4 * jj];
            o[4*jj]   = fmaf(p, kvv.x, o[4*jj]);
            o[4*jj+1] = fmaf(p, kvv.y, o[4*jj+1]);
            o[4*jj+2] = fmaf(p, kvv.z, o[4*jj+2]);
            o[4*jj+3] = fmaf(p, kvv.w, o[4*jj+3]);
        }
    }
    const float A = alpha_b * __expf(mhatq - mtrue) * FSCALE;
    const float dn = fmaxf(A * deno, 1e-4f);
    const float scale = A / dn;
    float4* og = (float4*)outp + ((size_t)b * SS + row) * 16;
    #pragma unroll
    for (int u = 0; u < 16; ++u)
        og[u] = make_float4(o[4*u] * scale, o[4*u+1] * scale,
                            o[4*u+2] * scale, o[4*u+3] * scale);
}

extern "C" void kernel_launch(void* const* d_in, const int* in_sizes, int n_in,
                              void* d_out, int out_size, void* d_ws, size_t ws_size,
                              hipStream_t stream) {
    (void)in_sizes; (void)n_in; (void)out_size; (void)ws_size;
    const float* q = (const float*)d_in[0];
    const float* k = (const float*)d_in[1];
    const float* v = (const float*)d_in[2];
    const float* w = (const float*)d_in[3];
    float* out = (float*)d_out;
    float* ws = (float*)d_ws;

    hipMemsetAsync(d_ws, 0, WS_ZERO_BYTES, stream);
    k_stats<<<dim3(16, 64), 256, 0, stream>>>(k, ws + MSUM_OFF_F, (unsigned*)ws + NKEY_OFF_F);
    k_kv<<<dim3(4, 64), 512, 0, stream>>>(k, v, w, ws);
    k_out<<<dim3(8, 64), 512, 0, stream>>>(q, w, ws, out);
}